// Round 7
// baseline (64.640 us; speedup 1.0000x reference)
//
#include <hip/hip_runtime.h>

// Problem constants (match reference setup_inputs()).
#define NV     10000     // base mesh vertices (N)
#define MPTS   500000    // target points (M)
#define BATCH  128       // scalar fields (B)

#define BLOCK  512       // threads per block (8 waves) -> 2 blocks/CU
#define G      2         // float4-groups of m per thread -> 8 m/thread
#define MBLK   (BLOCK * 4 * G)    // 4096 m per block
#define BPB    32                 // rows per block
#define BSPLIT (BATCH / BPB)      // 4 batch-split blocks per m-slice
#define PAIRS  (BPB / 2)          // 16 single-buffered pair-phases
#define NGROUPS ((MPTS + MBLK - 1) / MBLK)   // 123 m-slices
#define GRID   512                // 8 XCDs x 64; pads exit -> 492 active (~2/CU)

typedef float v4f __attribute__((ext_vector_type(4)));  // native clang vector
typedef int   v4i __attribute__((ext_vector_type(4)));

// Barrier that waits only for LDS ops (lgkmcnt) — NOT vmcnt. Nontemporal
// stores stay in flight across phases (nobody reads them); stage() global
// loads are consumed by ds_writes whose data-dep waits the compiler inserts.
__device__ inline void lds_barrier() {
    asm volatile("s_waitcnt lgkmcnt(0)" ::: "memory");
    __builtin_amdgcn_sched_barrier(0);
    __builtin_amdgcn_s_barrier();
}

// Two f-rows interleaved as float2 in LDS; ONE 80,000 B buffer per block.
// Two 512-thread blocks co-resident per CU (2x80 KB = 160 KB LDS): the
// sibling block's compute covers this block's stage/barrier stalls (TLP
// replaces the old intra-block double-buffer).
__global__ __launch_bounds__(BLOCK, 4)
void bary_interp_kernel(const float* __restrict__ f,    // (B, N)
                        const int*   __restrict__ tri,  // (M, 3)
                        const float* __restrict__ w,    // (M, 3)
                        float*       __restrict__ out)  // (B, M)
{
    __shared__ v4f buf4[NV / 2];   // viewed as float2 row2[NV]

    // XCD-grouped bijective mapping (dispatcher: XCD = blockIdx % 8, m09).
    // The BSPLIT=4 blocks sharing one m-slice (same tri/w bytes) land on the
    // SAME XCD so its L2 serves the re-reads.
    const int bid = (int)blockIdx.x;
    const int xcd = bid & 7;
    const int seq = bid >> 3;                // 0..63 within this XCD
    const int g   = xcd * 16 + (seq >> 2);   // m-slice 0..127
    const int y   = seq & 3;                 // batch-split 0..3
    if (g >= NGROUPS) return;                // pad blocks exit

    const int tid    = (int)threadIdx.x;
    const int m_base = g * MBLK;
    const int b0     = y * BPB;

    // ---- Load this thread's indices/weights once (vectorized int4/float4).
    int   idx[G][12];
    float wt [G][12];
    bool  valid[G];
#pragma unroll
    for (int gg = 0; gg < G; ++gg) {
        const int m = m_base + gg * (BLOCK * 4) + tid * 4;
        valid[gg] = (m < MPTS);           // M % 4 == 0, m % 4 == 0
        if (valid[gg]) {
            const v4i* ti = reinterpret_cast<const v4i*>(tri + 3 * (size_t)m);
            const v4f* wi = reinterpret_cast<const v4f*>(w + 3 * (size_t)m);
#pragma unroll
            for (int q = 0; q < 3; ++q) {
                const v4i a  = ti[q];
                const v4f bv = wi[q];
#pragma unroll
                for (int e = 0; e < 4; ++e) {
                    idx[gg][4*q+e] = a[e];
                    wt [gg][4*q+e] = bv[e];
                }
            }
        } else {
#pragma unroll
            for (int q = 0; q < 12; ++q) { idx[gg][q] = 0; wt[gg][q] = 0.0f; }
        }
    }

    for (int p = 0; p < PAIRS; ++p) {
        const int b = b0 + 2 * p;

        if (p) lds_barrier();   // all reads of buf4 done before overwrite

        // ---- Stage rows (b, b+1) interleaved: row2[n] = {f[b][n], f[b+1][n]}.
        {
            const v4f* fa = reinterpret_cast<const v4f*>(f + (size_t)b * NV);
            const v4f* fb = reinterpret_cast<const v4f*>(f + (size_t)(b + 1) * NV);
            for (int i = tid; i < NV / 4; i += BLOCK) {
                const v4f a = fa[i];
                const v4f c = fb[i];
                v4f lo = { a.x, c.x, a.y, c.y };
                v4f hi = { a.z, c.z, a.w, c.w };
                buf4[2*i+0] = lo;
                buf4[2*i+1] = hi;
            }
        }
        lds_barrier();          // staging visible to all waves

        const float2* row2 = reinterpret_cast<const float2*>(buf4);
        float* oa = out + (size_t)b * MPTS;
        float* ob = oa + MPTS;

#pragma unroll
        for (int gg = 0; gg < G; ++gg) {
            if (valid[gg]) {
                const int m = m_base + gg * (BLOCK * 4) + tid * 4;
                v4f ra, rc;
#pragma unroll
                for (int e = 0; e < 4; ++e) {
                    const float2 v0 = row2[idx[gg][3*e+0]];
                    const float2 v1 = row2[idx[gg][3*e+1]];
                    const float2 v2 = row2[idx[gg][3*e+2]];
                    ra[e] = v0.x*wt[gg][3*e+0] + v1.x*wt[gg][3*e+1] + v2.x*wt[gg][3*e+2];
                    rc[e] = v0.y*wt[gg][3*e+0] + v1.y*wt[gg][3*e+1] + v2.y*wt[gg][3*e+2];
                }
                __builtin_nontemporal_store(ra, reinterpret_cast<v4f*>(oa + m));
                __builtin_nontemporal_store(rc, reinterpret_cast<v4f*>(ob + m));
            }
        }
        // No barrier here: stores stay in flight; loop-top barrier protects
        // buf4 reuse.
    }
}

extern "C" void kernel_launch(void* const* d_in, const int* in_sizes, int n_in,
                              void* d_out, int out_size, void* d_ws, size_t ws_size,
                              hipStream_t stream) {
    const float* f   = (const float*)d_in[0];   // (B, N)  float32
    const int*   tri = (const int*)  d_in[1];   // (M, 3)  int32
    const float* w   = (const float*)d_in[2];   // (M, 3)  float32
    float*       out = (float*)d_out;           // (B, M)  float32

    bary_interp_kernel<<<dim3(GRID), BLOCK, 0, stream>>>(f, tri, w, out);
}